// Round 4
// baseline (721.076 us; speedup 1.0000x reference)
//
#include <hip/hip_runtime.h>
#include <hip/hip_bf16.h>

#define VOCAB 50257
#define CVOCAB 64
#define OUTW (VOCAB + CVOCAB)   // 50321
#define DDIM 1024
#define NROWS 2048
#define SLEN 128
#define NVT 393                  // fallback path: ceil(50257/128)
#define NVT2 197                 // fast path: ceil(50257/256)
#define VOCABP2 (NVT2 * 256)     // 50432 padded vocab rows

typedef __attribute__((ext_vector_type(8))) short bf16x8;
typedef __attribute__((ext_vector_type(4))) float f32x4;

__device__ __forceinline__ unsigned short f2bf(float f) {
  union { float f; unsigned u; } x; x.f = f;
  unsigned r = x.u + 0x7FFFu + ((x.u >> 16) & 1u);
  return (unsigned short)(r >> 16);
}

__device__ __forceinline__ void gload_lds16(const void* g, void* l) {
  __builtin_amdgcn_global_load_lds((const __attribute__((address_space(1))) void*)g,
                                   (__attribute__((address_space(3))) void*)l, 16, 0, 0);
}

// ---------------- p_copy = sigmoid(hidden @ W_copy^T + b_copy) ----------------
__global__ __launch_bounds__(256) void k_pcopy(const float* __restrict__ hidden,
                                               const float* __restrict__ Wc,
                                               const float* __restrict__ bc,
                                               float* __restrict__ pc) {
  int n = blockIdx.x * 4 + (threadIdx.x >> 6);
  int lane = threadIdx.x & 63;
  const float4* h = (const float4*)(hidden + (size_t)n * DDIM);
  const float4* w = (const float4*)Wc;
  float s = 0.0f;
  for (int i = lane; i < DDIM / 4; i += 64) {
    float4 a = h[i], b = w[i];
    s += a.x * b.x + a.y * b.y + a.z * b.z + a.w * b.w;
  }
  #pragma unroll
  for (int m = 1; m < 64; m <<= 1) s += __shfl_xor(s, m);
  if (lane == 0) pc[n] = 1.0f / (1.0f + __expf(-(s + bc[0])));
}

// ---------------- f32 -> bf16 pre-conversion ---------------------------------
__global__ __launch_bounds__(256) void k_cvtA(const float* __restrict__ src,
                                              ushort* __restrict__ dst) {
  int i = blockIdx.x * 256 + threadIdx.x;   // one float4 per thread
  float4 v = *(const float4*)(src + (size_t)i * 4);
  ushort4 h;
  h.x = f2bf(v.x); h.y = f2bf(v.y); h.z = f2bf(v.z); h.w = f2bf(v.w);
  *(ushort4*)(dst + (size_t)i * 4) = h;
}

__global__ __launch_bounds__(256) void k_cvtW(const float* __restrict__ Wg,
                                              ushort* __restrict__ Wbf) {
  int row = blockIdx.x;                      // 0..VOCABP2-1
  int t = threadIdx.x;                       // 256 threads x 4 elems = 1024
  ushort4 h = make_ushort4(0, 0, 0, 0);
  if (row < VOCAB) {
    float4 v = *(const float4*)(Wg + (size_t)row * DDIM + t * 4);
    h.x = f2bf(v.x); h.y = f2bf(v.y); h.z = f2bf(v.z); h.w = f2bf(v.w);
  }
  *(ushort4*)(Wbf + (size_t)row * DDIM + t * 4) = h;
}

// ---------------- 256x256 8-phase GEMM: e = exp(A@W^T + bg), row sums --------
// LDS per operand: [buf 2][khalf 2][256 rows][32 k] bf16 (16 KB half-tiles).
// Row stride 64 B -> natural bank spread, no swizzle needed.
// Phase (buf,h,s): reads A rows wr*128+h*64+rf*16, B cols wn*64+cf*16, K-half s.
// Stage schedule per iteration i (tiles 2i in buf0, 2i+1 in buf1):
//  ph1:A(2i+1,k1) ph2:B(2i+1,k1) ph3:A(2i+2,k0) ph4:B(2i+2,k0)+vmcnt(4)
//  ph5:A(2i+2,k1) ph6:B(2i+2,k1) ph7:A(2i+3,k0) ph8:B(2i+3,k0)+vmcnt(4)
__global__ __launch_bounds__(512, 2) void k_gemm3(const ushort* __restrict__ A,
                                                  const ushort* __restrict__ W,
                                                  const float* __restrict__ bg,
                                                  float* __restrict__ out,
                                                  float* __restrict__ partial) {
  __shared__ __align__(16) ushort sA[2][2][256 * 32];
  __shared__ __align__(16) ushort sB[2][2][256 * 32];

  const int tid = threadIdx.x;
  const int lane = tid & 63;
  const int w = tid >> 6;          // 0..7
  const int wr = w >> 2, wn = w & 3;
  const int lrow = lane & 15, kgrp = lane >> 4;

  // bijective XCD swizzle: 1576 = 8 * 197; same-XCD neighbors share vt (W panel)
  int swz = (blockIdx.x & 7) * 197 + (blockIdx.x >> 3);
  const int mt = swz & 7, vt = swz >> 3;
  const int m0 = mt * 256;
  const int v0 = vt * 256;

  const int srow = tid >> 2, scq = tid & 3;   // staging: row, 16B-chunk in row

  #define STAGE_A(t, s) { \
    int _b = (t) & 1; \
    gload_lds16(A + (size_t)(m0 + srow) * DDIM + (t) * 64 + (s) * 32 + scq * 8, \
                &sA[_b][s][(size_t)tid * 8]); \
    gload_lds16(A + (size_t)(m0 + 128 + srow) * DDIM + (t) * 64 + (s) * 32 + scq * 8, \
                &sA[_b][s][(size_t)(512 + tid) * 8]); \
  }
  #define STAGE_B(t, s) { \
    int _b = (t) & 1; \
    gload_lds16(W + (size_t)(v0 + srow) * DDIM + (t) * 64 + (s) * 32 + scq * 8, \
                &sB[_b][s][(size_t)tid * 8]); \
    gload_lds16(W + (size_t)(v0 + 128 + srow) * DDIM + (t) * 64 + (s) * 32 + scq * 8, \
                &sB[_b][s][(size_t)(512 + tid) * 8]); \
  }

  f32x4 acc[8][4] = {};

  // prologue: tile0 fully + tile1 k0 halves
  STAGE_A(0, 0); STAGE_B(0, 0);
  STAGE_A(0, 1); STAGE_B(0, 1);
  STAGE_A(1, 0); STAGE_B(1, 0);
  asm volatile("s_waitcnt vmcnt(4)" ::: "memory");
  __builtin_amdgcn_s_barrier();

  #define PHASE(buf, h, s, STAGE_STMT, WAIT_STMT) { \
    bf16x8 af[4], bfr[4]; \
    const ushort* pa = &sA[buf][s][0]; \
    const ushort* pb = &sB[buf][s][0]; \
    _Pragma("unroll") \
    for (int rf = 0; rf < 4; rf++) \
      af[rf] = *(const bf16x8*)(pa + (wr * 128 + (h) * 64 + rf * 16 + lrow) * 32 + kgrp * 8); \
    _Pragma("unroll") \
    for (int cf = 0; cf < 4; cf++) \
      bfr[cf] = *(const bf16x8*)(pb + (wn * 64 + cf * 16 + lrow) * 32 + kgrp * 8); \
    STAGE_STMT; \
    __builtin_amdgcn_s_barrier(); \
    __builtin_amdgcn_s_setprio(1); \
    _Pragma("unroll") \
    for (int rf = 0; rf < 4; rf++) \
      _Pragma("unroll") \
      for (int cf = 0; cf < 4; cf++) \
        acc[(h) * 4 + rf][cf] = \
          __builtin_amdgcn_mfma_f32_16x16x32_bf16(af[rf], bfr[cf], acc[(h) * 4 + rf][cf], 0, 0, 0); \
    __builtin_amdgcn_s_setprio(0); \
    WAIT_STMT; \
    __builtin_amdgcn_s_barrier(); \
  }

  for (int i = 0; i < 8; i++) {
    const int t1 = 2 * i + 1, t2 = 2 * i + 2, t3 = 2 * i + 3;
    const bool pf = (i < 7);
    PHASE(0, 0, 0, { STAGE_A(t1, 1); }, {});
    PHASE(0, 1, 0, { STAGE_B(t1, 1); }, {});
    PHASE(0, 0, 1, { if (pf) STAGE_A(t2, 0); }, {});
    PHASE(0, 1, 1, { if (pf) STAGE_B(t2, 0); },
          { if (pf) asm volatile("s_waitcnt vmcnt(4)" ::: "memory");
            else    asm volatile("s_waitcnt vmcnt(0)" ::: "memory"); });
    PHASE(1, 0, 0, { if (pf) STAGE_A(t2, 1); }, {});
    PHASE(1, 1, 0, { if (pf) STAGE_B(t2, 1); }, {});
    PHASE(1, 0, 1, { if (pf) STAGE_A(t3, 0); }, {});
    PHASE(1, 1, 1, { if (pf) STAGE_B(t3, 0); },
          { if (pf) asm volatile("s_waitcnt vmcnt(4)" ::: "memory"); });
  }

  asm volatile("s_waitcnt vmcnt(0)" ::: "memory");
  __syncthreads();
  float* psum = (float*)&sA[0][0][0];   // [4][256], aliases drained sA

  float bgv[4];
  int vcol[4];
  #pragma unroll
  for (int cf = 0; cf < 4; cf++) {
    vcol[cf] = v0 + wn * 64 + cf * 16 + lrow;
    bgv[cf] = (vcol[cf] < VOCAB) ? bg[vcol[cf]] : 0.0f;
  }
  #pragma unroll
  for (int a = 0; a < 8; a++) {
    const int h = a >> 2, rf = a & 3;
    #pragma unroll
    for (int r = 0; r < 4; r++) {
      int lr = wr * 128 + h * 64 + rf * 16 + kgrp * 4 + r;
      int row = m0 + lr;
      float s = 0.0f;
      #pragma unroll
      for (int cf = 0; cf < 4; cf++) {
        int v = vcol[cf];
        float e = 0.0f;
        if (v < VOCAB && v != 0) e = __expf(acc[a][cf][r] + bgv[cf]);
        if (v < VOCAB) __builtin_nontemporal_store(e, &out[(size_t)row * OUTW + v]);
        s += e;
      }
      s += __shfl_xor(s, 1); s += __shfl_xor(s, 2);
      s += __shfl_xor(s, 4); s += __shfl_xor(s, 8);
      if (lrow == 0) psum[wn * 256 + lr] = s;
    }
  }
  __syncthreads();
  if (tid < 256)
    partial[(size_t)vt * NROWS + m0 + tid] =
        psum[tid] + psum[256 + tid] + psum[512 + tid] + psum[768 + tid];
  #undef PHASE
  #undef STAGE_A
  #undef STAGE_B
}

// ---------------- fallback GEMM (round-1, f32 inputs) ------------------------
__global__ __launch_bounds__(256) void k_gemm(const float* __restrict__ hidden,
                                              const float* __restrict__ Wg,
                                              const float* __restrict__ bg,
                                              float* __restrict__ out,
                                              float* __restrict__ partial) {
  __shared__ __align__(16) unsigned char smemA[128 * 64 * 2];
  __shared__ __align__(16) unsigned char smemB[128 * 64 * 2];
  __shared__ float psum[2][128];

  const int tid = threadIdx.x;
  const int lane = tid & 63;
  const int wid = tid >> 6;
  const int wr = wid >> 1, wc = wid & 1;
  const int lrow = lane & 15, kgrp = lane >> 4;
  const int m0 = blockIdx.x * 128;
  const int vt = blockIdx.y;
  const int v0 = vt * 128;

  f32x4 acc[4][4] = {};

  for (int kt = 0; kt < 16; kt++) {
    const int k0 = kt * 64;
    #pragma unroll
    for (int i = 0; i < 8; i++) {
      int f = i * 256 + tid;
      int row = f >> 4;
      int kq = (f & 15) << 2;
      float4 v = *(const float4*)(hidden + (size_t)(m0 + row) * DDIM + k0 + kq);
      ushort4 h;
      h.x = f2bf(v.x); h.y = f2bf(v.y); h.z = f2bf(v.z); h.w = f2bf(v.w);
      *(ushort4*)(smemA + row * 128 + ((kq << 1) ^ ((row & 7) << 4))) = h;
    }
    #pragma unroll
    for (int i = 0; i < 8; i++) {
      int f = i * 256 + tid;
      int row = f >> 4;
      int kq = (f & 15) << 2;
      float4 v = make_float4(0.f, 0.f, 0.f, 0.f);
      if (v0 + row < VOCAB)
        v = *(const float4*)(Wg + (size_t)(v0 + row) * DDIM + k0 + kq);
      ushort4 h;
      h.x = f2bf(v.x); h.y = f2bf(v.y); h.z = f2bf(v.z); h.w = f2bf(v.w);
      *(ushort4*)(smemB + row * 128 + ((kq << 1) ^ ((row & 7) << 4))) = h;
    }
    __syncthreads();
    #pragma unroll
    for (int ks = 0; ks < 2; ks++) {
      const int kb = (ks * 32 + kgrp * 8) * 2;
      bf16x8 af[4], bfr[4];
      #pragma unroll
      for (int i = 0; i < 4; i++) {
        int ar = wr * 64 + i * 16 + lrow;
        af[i] = *(const bf16x8*)(smemA + ar * 128 + (kb ^ ((ar & 7) << 4)));
        int br = wc * 64 + i * 16 + lrow;
        bfr[i] = *(const bf16x8*)(smemB + br * 128 + (kb ^ ((br & 7) << 4)));
      }
      #pragma unroll
      for (int i = 0; i < 4; i++)
        #pragma unroll
        for (int j = 0; j < 4; j++)
          acc[i][j] = __builtin_amdgcn_mfma_f32_16x16x32_bf16(af[i], bfr[j], acc[i][j], 0, 0, 0);
    }
    __syncthreads();
  }

  float bgv[4];
  int vcol[4];
  #pragma unroll
  for (int j = 0; j < 4; j++) {
    vcol[j] = v0 + wc * 64 + j * 16 + lrow;
    bgv[j] = (vcol[j] < VOCAB) ? bg[vcol[j]] : 0.0f;
  }
  #pragma unroll
  for (int i = 0; i < 4; i++) {
    #pragma unroll
    for (int r = 0; r < 4; r++) {
      int row = m0 + wr * 64 + i * 16 + kgrp * 4 + r;
      float s = 0.0f;
      #pragma unroll
      for (int j = 0; j < 4; j++) {
        int v = vcol[j];
        float e = 0.0f;
        if (v < VOCAB && v != 0) e = __expf(acc[i][j][r] + bgv[j]);
        if (v < VOCAB) out[(size_t)row * OUTW + v] = e;
        s += e;
      }
      s += __shfl_xor(s, 1); s += __shfl_xor(s, 2);
      s += __shfl_xor(s, 4); s += __shfl_xor(s, 8);
      if ((lane & 15) == 0) psum[wc][wr * 64 + i * 16 + kgrp * 4 + r] = s;
    }
  }
  __syncthreads();
  if (tid < 128)
    partial[(size_t)vt * NROWS + m0 + tid] = psum[0][tid] + psum[1][tid];
}

// ---------------- reduce partials -> scale = (1-pc)/sum ----------------------
__global__ __launch_bounds__(256) void k_reduce(const float* __restrict__ partial,
                                                const float* __restrict__ pc,
                                                float* __restrict__ scale, int nvt) {
  int n = blockIdx.x * 256 + threadIdx.x;
  float s = 0.0f;
  for (int t = 0; t < nvt; t++) s += partial[(size_t)t * NROWS + n];
  scale[n] = (1.0f - pc[n]) / s;
}

// ---------------- scale gen region in place ----------------------------------
__global__ __launch_bounds__(256) void k_scale(float* __restrict__ out,
                                               const float* __restrict__ scale) {
  int n = blockIdx.x;
  float sc = scale[n];
  size_t base = (size_t)n * OUTW;
  int off = (int)((4 - (base & 3)) & 3);
  for (int c = threadIdx.x; c < off; c += 256) out[base + c] *= sc;
  int nv = (VOCAB - off) >> 2;
  f32x4* p = (f32x4*)(out + base + off);
  for (int i = threadIdx.x; i < nv; i += 256) {
    f32x4 v = __builtin_nontemporal_load(&p[i]);
    v *= sc;
    __builtin_nontemporal_store(v, &p[i]);
  }
  for (int c = off + (nv << 2) + threadIdx.x; c < VOCAB; c += 256) out[base + c] *= sc;
}

// ---------------- copy probs: out[:, VOCAB:] = (attn*pc) @ src_map -----------
__global__ __launch_bounds__(64) void k_copy(const float* __restrict__ attn,
                                             const float* __restrict__ src_map,
                                             const float* __restrict__ pc,
                                             float* __restrict__ out) {
  int n = blockIdx.x;
  int c = threadIdx.x;  // 0..63
  int b = n & 31;
  __shared__ float arow[SLEN];
  arow[c] = attn[(size_t)n * SLEN + c];
  arow[c + 64] = attn[(size_t)n * SLEN + 64 + c];
  __syncthreads();
  float s = 0.0f;
  for (int sp = 0; sp < SLEN; sp++)
    s += arow[sp] * src_map[((size_t)sp * 32 + b) * CVOCAB + c];
  out[(size_t)n * OUTW + VOCAB + c] = s * pc[n];
}

extern "C" void kernel_launch(void* const* d_in, const int* in_sizes, int n_in,
                              void* d_out, int out_size, void* d_ws, size_t ws_size,
                              hipStream_t stream) {
  const float* hidden = (const float*)d_in[0];
  const float* attn   = (const float*)d_in[1];
  const float* srcmap = (const float*)d_in[2];
  const float* Wg     = (const float*)d_in[3];
  const float* bg     = (const float*)d_in[4];
  const float* Wc     = (const float*)d_in[5];
  const float* bc     = (const float*)d_in[6];
  float* out = (float*)d_out;

  char* ws = (char*)d_ws;
  float* pc      = (float*)ws;                       // 2048 f32
  float* scale   = (float*)(ws + 8192);              // 2048 f32
  float* partial = (float*)(ws + 16384);             // max(NVT,NVT2)*2048 f32
  size_t partEnd = 16384 + (size_t)NVT * NROWS * 4;  // 3,235,840
  ushort* Abf = (ushort*)(ws + partEnd);             // 2048*1024 bf16
  size_t aEnd = partEnd + (size_t)NROWS * DDIM * 2;
  ushort* Wbf = (ushort*)(ws + aEnd);                // VOCABP2*1024 bf16
  size_t need = aEnd + (size_t)VOCABP2 * DDIM * 2;

  k_pcopy<<<NROWS / 4, 256, 0, stream>>>(hidden, Wc, bc, pc);
  if (ws_size >= need) {
    k_cvtA<<<(NROWS * DDIM / 4) / 256, 256, 0, stream>>>(hidden, Abf);
    k_cvtW<<<VOCABP2, 256, 0, stream>>>(Wg, Wbf);
    k_gemm3<<<8 * NVT2, 512, 0, stream>>>(Abf, Wbf, bg, out, partial);
    k_reduce<<<NROWS / 256, 256, 0, stream>>>(partial, pc, scale, NVT2);
  } else {
    k_gemm<<<dim3(NROWS / 128, NVT), 256, 0, stream>>>(hidden, Wg, bg, out, partial);
    k_reduce<<<NROWS / 256, 256, 0, stream>>>(partial, pc, scale, NVT);
  }
  k_scale<<<NROWS, 256, 0, stream>>>(out, scale);
  k_copy<<<NROWS, 64, 0, stream>>>(attn, srcmap, pc, out);
}

// Round 5
// 632.142 us; speedup vs baseline: 1.1407x; 1.1407x over previous
//
#include <hip/hip_runtime.h>
#include <hip/hip_bf16.h>

#define VOCAB 50257
#define CVOCAB 64
#define OUTW (VOCAB + CVOCAB)   // 50321
#define DDIM 1024
#define NROWS 2048
#define SLEN 128
#define NVT 393                  // fallback path: ceil(50257/128)
#define NVT2 197                 // fast path: ceil(50257/256)
#define VOCABP2 (NVT2 * 256)     // 50432 padded vocab rows

typedef __attribute__((ext_vector_type(8))) short bf16x8;
typedef __attribute__((ext_vector_type(4))) float f32x4;

__device__ __forceinline__ unsigned short f2bf(float f) {
  union { float f; unsigned u; } x; x.f = f;
  unsigned r = x.u + 0x7FFFu + ((x.u >> 16) & 1u);
  return (unsigned short)(r >> 16);
}

__device__ __forceinline__ void gload_lds16(const void* g, void* l) {
  __builtin_amdgcn_global_load_lds((const __attribute__((address_space(1))) void*)g,
                                   (__attribute__((address_space(3))) void*)l, 16, 0, 0);
}

// ---------------- p_copy = sigmoid(hidden @ W_copy^T + b_copy) ----------------
__global__ __launch_bounds__(256) void k_pcopy(const float* __restrict__ hidden,
                                               const float* __restrict__ Wc,
                                               const float* __restrict__ bc,
                                               float* __restrict__ pc) {
  int n = blockIdx.x * 4 + (threadIdx.x >> 6);
  int lane = threadIdx.x & 63;
  const float4* h = (const float4*)(hidden + (size_t)n * DDIM);
  const float4* w = (const float4*)Wc;
  float s = 0.0f;
  for (int i = lane; i < DDIM / 4; i += 64) {
    float4 a = h[i], b = w[i];
    s += a.x * b.x + a.y * b.y + a.z * b.z + a.w * b.w;
  }
  #pragma unroll
  for (int m = 1; m < 64; m <<= 1) s += __shfl_xor(s, m);
  if (lane == 0) pc[n] = 1.0f / (1.0f + __expf(-(s + bc[0])));
}

// ---------------- f32 -> bf16 pre-conversion ---------------------------------
__global__ __launch_bounds__(256) void k_cvtA(const float* __restrict__ src,
                                              ushort* __restrict__ dst) {
  int i = blockIdx.x * 256 + threadIdx.x;   // one float4 per thread
  float4 v = *(const float4*)(src + (size_t)i * 4);
  ushort4 h;
  h.x = f2bf(v.x); h.y = f2bf(v.y); h.z = f2bf(v.z); h.w = f2bf(v.w);
  *(ushort4*)(dst + (size_t)i * 4) = h;
}

__global__ __launch_bounds__(256) void k_cvtW(const float* __restrict__ Wg,
                                              ushort* __restrict__ Wbf) {
  int row = blockIdx.x;                      // 0..VOCABP2-1
  int t = threadIdx.x;                       // 256 threads x 4 elems = 1024
  ushort4 h = make_ushort4(0, 0, 0, 0);
  if (row < VOCAB) {
    float4 v = *(const float4*)(Wg + (size_t)row * DDIM + t * 4);
    h.x = f2bf(v.x); h.y = f2bf(v.y); h.z = f2bf(v.z); h.w = f2bf(v.w);
  }
  *(ushort4*)(Wbf + (size_t)row * DDIM + t * 4) = h;
}

// ---------------- 256x256 8-phase GEMM: e = exp(A@W^T + bg), row sums --------
// LDS per operand: [buf 2][khalf 2][256 rows][32 k] bf16 (16 KB half-tiles).
// T2 swizzle (both-sides, rule #21): logical 16B chunk (row,cq) lives at
// cq ^ ((row>>1)&3). Bank-group = 4*(row&1) + cq' -> any 8 consecutive lanes
// (rows r..r+7, fixed kgrp) hit all 8 distinct groups: conflict-free.
// Staged via pre-swizzled GLOBAL source (LDS dest linear), read with same XOR.
__global__ __launch_bounds__(512, 2) void k_gemm3(const ushort* __restrict__ A,
                                                  const ushort* __restrict__ W,
                                                  const float* __restrict__ bg,
                                                  float* __restrict__ out,
                                                  float* __restrict__ partial) {
  __shared__ __align__(16) ushort sA[2][2][256 * 32];
  __shared__ __align__(16) ushort sB[2][2][256 * 32];

  const int tid = threadIdx.x;
  const int lane = tid & 63;
  const int w = tid >> 6;          // 0..7
  const int wr = w >> 2, wn = w & 3;
  const int lrow = lane & 15, kgrp = lane >> 4;

  // bijective XCD swizzle: 1576 = 8 * 197; same-XCD neighbors share vt (W panel)
  int swz = (blockIdx.x & 7) * 197 + (blockIdx.x >> 3);
  const int mt = swz & 7, vt = swz >> 3;
  const int m0 = mt * 256;
  const int v0 = vt * 256;

  const int srow = tid >> 2, scq = tid & 3;          // staging row, chunk
  const int scq_sw = scq ^ ((srow >> 1) & 3);        // inverse(=same) swizzle on source

  #define STAGE_A(t, s) { \
    int _b = (t) & 1; \
    gload_lds16(A + (size_t)(m0 + srow) * DDIM + (t) * 64 + (s) * 32 + scq_sw * 8, \
                &sA[_b][s][(size_t)tid * 8]); \
    gload_lds16(A + (size_t)(m0 + 128 + srow) * DDIM + (t) * 64 + (s) * 32 + scq_sw * 8, \
                &sA[_b][s][(size_t)(512 + tid) * 8]); \
  }
  #define STAGE_B(t, s) { \
    int _b = (t) & 1; \
    gload_lds16(W + (size_t)(v0 + srow) * DDIM + (t) * 64 + (s) * 32 + scq_sw * 8, \
                &sB[_b][s][(size_t)tid * 8]); \
    gload_lds16(W + (size_t)(v0 + 128 + srow) * DDIM + (t) * 64 + (s) * 32 + scq_sw * 8, \
                &sB[_b][s][(size_t)(512 + tid) * 8]); \
  }

  // precomputed swizzled read offsets (ushort units)
  int aoff[2][4], boff[4];
  #pragma unroll
  for (int h = 0; h < 2; h++)
    #pragma unroll
    for (int rf = 0; rf < 4; rf++) {
      int row = wr * 128 + h * 64 + rf * 16 + lrow;
      aoff[h][rf] = row * 32 + (kgrp ^ ((row >> 1) & 3)) * 8;
    }
  #pragma unroll
  for (int cf = 0; cf < 4; cf++) {
    int row = wn * 64 + cf * 16 + lrow;
    boff[cf] = row * 32 + (kgrp ^ ((row >> 1) & 3)) * 8;
  }

  f32x4 acc[8][4] = {};

  // prologue: tile0 fully + tile1 k0 halves
  STAGE_A(0, 0); STAGE_B(0, 0);
  STAGE_A(0, 1); STAGE_B(0, 1);
  STAGE_A(1, 0); STAGE_B(1, 0);
  asm volatile("s_waitcnt vmcnt(4)" ::: "memory");
  __builtin_amdgcn_s_barrier();

  #define PHASE(buf, h, s, STAGE_STMT, WAIT_STMT) { \
    bf16x8 af[4], bfr[4]; \
    const ushort* pa = &sA[buf][s][0]; \
    const ushort* pb = &sB[buf][s][0]; \
    _Pragma("unroll") \
    for (int rf = 0; rf < 4; rf++) \
      af[rf] = *(const bf16x8*)(pa + aoff[(h)][rf]); \
    _Pragma("unroll") \
    for (int cf = 0; cf < 4; cf++) \
      bfr[cf] = *(const bf16x8*)(pb + boff[cf]); \
    STAGE_STMT; \
    __builtin_amdgcn_s_barrier(); \
    __builtin_amdgcn_s_setprio(1); \
    _Pragma("unroll") \
    for (int rf = 0; rf < 4; rf++) \
      _Pragma("unroll") \
      for (int cf = 0; cf < 4; cf++) \
        acc[(h) * 4 + rf][cf] = \
          __builtin_amdgcn_mfma_f32_16x16x32_bf16(af[rf], bfr[cf], acc[(h) * 4 + rf][cf], 0, 0, 0); \
    __builtin_amdgcn_s_setprio(0); \
    WAIT_STMT; \
    __builtin_amdgcn_s_barrier(); \
  }

  for (int i = 0; i < 8; i++) {
    const int t1 = 2 * i + 1, t2 = 2 * i + 2, t3 = 2 * i + 3;
    const bool pf = (i < 7);
    PHASE(0, 0, 0, { STAGE_A(t1, 1); }, {});
    PHASE(0, 1, 0, { STAGE_B(t1, 1); }, {});
    PHASE(0, 0, 1, { if (pf) STAGE_A(t2, 0); }, {});
    PHASE(0, 1, 1, { if (pf) STAGE_B(t2, 0); },
          { if (pf) asm volatile("s_waitcnt vmcnt(4)" ::: "memory");
            else    asm volatile("s_waitcnt vmcnt(0)" ::: "memory"); });
    PHASE(1, 0, 0, { if (pf) STAGE_A(t2, 1); }, {});
    PHASE(1, 1, 0, { if (pf) STAGE_B(t2, 1); }, {});
    PHASE(1, 0, 1, { if (pf) STAGE_A(t3, 0); }, {});
    PHASE(1, 1, 1, { if (pf) STAGE_B(t3, 0); },
          { if (pf) asm volatile("s_waitcnt vmcnt(4)" ::: "memory"); });
  }

  asm volatile("s_waitcnt vmcnt(0)" ::: "memory");
  __syncthreads();
  float* psum = (float*)&sA[0][0][0];   // [4][256], aliases drained sA

  float bgv[4];
  int vcol[4];
  #pragma unroll
  for (int cf = 0; cf < 4; cf++) {
    vcol[cf] = v0 + wn * 64 + cf * 16 + lrow;
    bgv[cf] = (vcol[cf] < VOCAB) ? bg[vcol[cf]] : 0.0f;
  }
  #pragma unroll
  for (int a = 0; a < 8; a++) {
    const int h = a >> 2, rf = a & 3;
    #pragma unroll
    for (int r = 0; r < 4; r++) {
      int lr = wr * 128 + h * 64 + rf * 16 + kgrp * 4 + r;
      int row = m0 + lr;
      float s = 0.0f;
      #pragma unroll
      for (int cf = 0; cf < 4; cf++) {
        int v = vcol[cf];
        float e = 0.0f;
        if (v < VOCAB && v != 0) e = __expf(acc[a][cf][r] + bgv[cf]);
        if (v < VOCAB) out[(size_t)row * OUTW + v] = e;
        s += e;
      }
      s += __shfl_xor(s, 1); s += __shfl_xor(s, 2);
      s += __shfl_xor(s, 4); s += __shfl_xor(s, 8);
      if (lrow == 0) psum[wn * 256 + lr] = s;
    }
  }
  __syncthreads();
  if (tid < 256)
    partial[(size_t)vt * NROWS + m0 + tid] =
        psum[tid] + psum[256 + tid] + psum[512 + tid] + psum[768 + tid];
  #undef PHASE
  #undef STAGE_A
  #undef STAGE_B
}

// ---------------- fallback GEMM (round-1, f32 inputs) ------------------------
__global__ __launch_bounds__(256) void k_gemm(const float* __restrict__ hidden,
                                              const float* __restrict__ Wg,
                                              const float* __restrict__ bg,
                                              float* __restrict__ out,
                                              float* __restrict__ partial) {
  __shared__ __align__(16) unsigned char smemA[128 * 64 * 2];
  __shared__ __align__(16) unsigned char smemB[128 * 64 * 2];
  __shared__ float psum[2][128];

  const int tid = threadIdx.x;
  const int lane = tid & 63;
  const int wid = tid >> 6;
  const int wr = wid >> 1, wc = wid & 1;
  const int lrow = lane & 15, kgrp = lane >> 4;
  const int m0 = blockIdx.x * 128;
  const int vt = blockIdx.y;
  const int v0 = vt * 128;

  f32x4 acc[4][4] = {};

  for (int kt = 0; kt < 16; kt++) {
    const int k0 = kt * 64;
    #pragma unroll
    for (int i = 0; i < 8; i++) {
      int f = i * 256 + tid;
      int row = f >> 4;
      int kq = (f & 15) << 2;
      float4 v = *(const float4*)(hidden + (size_t)(m0 + row) * DDIM + k0 + kq);
      ushort4 h;
      h.x = f2bf(v.x); h.y = f2bf(v.y); h.z = f2bf(v.z); h.w = f2bf(v.w);
      *(ushort4*)(smemA + row * 128 + ((kq << 1) ^ ((row & 7) << 4))) = h;
    }
    #pragma unroll
    for (int i = 0; i < 8; i++) {
      int f = i * 256 + tid;
      int row = f >> 4;
      int kq = (f & 15) << 2;
      float4 v = make_float4(0.f, 0.f, 0.f, 0.f);
      if (v0 + row < VOCAB)
        v = *(const float4*)(Wg + (size_t)(v0 + row) * DDIM + k0 + kq);
      ushort4 h;
      h.x = f2bf(v.x); h.y = f2bf(v.y); h.z = f2bf(v.z); h.w = f2bf(v.w);
      *(ushort4*)(smemB + row * 128 + ((kq << 1) ^ ((row & 7) << 4))) = h;
    }
    __syncthreads();
    #pragma unroll
    for (int ks = 0; ks < 2; ks++) {
      const int kb = (ks * 32 + kgrp * 8) * 2;
      bf16x8 af[4], bfr[4];
      #pragma unroll
      for (int i = 0; i < 4; i++) {
        int ar = wr * 64 + i * 16 + lrow;
        af[i] = *(const bf16x8*)(smemA + ar * 128 + (kb ^ ((ar & 7) << 4)));
        int br = wc * 64 + i * 16 + lrow;
        bfr[i] = *(const bf16x8*)(smemB + br * 128 + (kb ^ ((br & 7) << 4)));
      }
      #pragma unroll
      for (int i = 0; i < 4; i++)
        #pragma unroll
        for (int j = 0; j < 4; j++)
          acc[i][j] = __builtin_amdgcn_mfma_f32_16x16x32_bf16(af[i], bfr[j], acc[i][j], 0, 0, 0);
    }
    __syncthreads();
  }

  float bgv[4];
  int vcol[4];
  #pragma unroll
  for (int j = 0; j < 4; j++) {
    vcol[j] = v0 + wc * 64 + j * 16 + lrow;
    bgv[j] = (vcol[j] < VOCAB) ? bg[vcol[j]] : 0.0f;
  }
  #pragma unroll
  for (int i = 0; i < 4; i++) {
    #pragma unroll
    for (int r = 0; r < 4; r++) {
      int row = m0 + wr * 64 + i * 16 + kgrp * 4 + r;
      float s = 0.0f;
      #pragma unroll
      for (int j = 0; j < 4; j++) {
        int v = vcol[j];
        float e = 0.0f;
        if (v < VOCAB && v != 0) e = __expf(acc[i][j][r] + bgv[j]);
        if (v < VOCAB) out[(size_t)row * OUTW + v] = e;
        s += e;
      }
      s += __shfl_xor(s, 1); s += __shfl_xor(s, 2);
      s += __shfl_xor(s, 4); s += __shfl_xor(s, 8);
      if ((lane & 15) == 0) psum[wc][wr * 64 + i * 16 + kgrp * 4 + r] = s;
    }
  }
  __syncthreads();
  if (tid < 128)
    partial[(size_t)vt * NROWS + m0 + tid] = psum[0][tid] + psum[1][tid];
}

// ---------------- reduce partials -> scale = (1-pc)/sum ----------------------
__global__ __launch_bounds__(256) void k_reduce(const float* __restrict__ partial,
                                                const float* __restrict__ pc,
                                                float* __restrict__ scale, int nvt) {
  int n = blockIdx.x * 256 + threadIdx.x;
  float s = 0.0f;
  for (int t = 0; t < nvt; t++) s += partial[(size_t)t * NROWS + n];
  scale[n] = (1.0f - pc[n]) / s;
}

// ---------------- scale gen region in place ----------------------------------
__global__ __launch_bounds__(256) void k_scale(float* __restrict__ out,
                                               const float* __restrict__ scale) {
  int n = blockIdx.x;
  float sc = scale[n];
  size_t base = (size_t)n * OUTW;
  int off = (int)((4 - (base & 3)) & 3);
  for (int c = threadIdx.x; c < off; c += 256) out[base + c] *= sc;
  int nv = (VOCAB - off) >> 2;
  f32x4* p = (f32x4*)(out + base + off);
  for (int i = threadIdx.x; i < nv; i += 256) {
    f32x4 v = __builtin_nontemporal_load(&p[i]);
    v *= sc;
    __builtin_nontemporal_store(v, &p[i]);
  }
  for (int c = off + (nv << 2) + threadIdx.x; c < VOCAB; c += 256) out[base + c] *= sc;
}

// ---------------- copy probs: out[:, VOCAB:] = (attn*pc) @ src_map -----------
__global__ __launch_bounds__(64) void k_copy(const float* __restrict__ attn,
                                             const float* __restrict__ src_map,
                                             const float* __restrict__ pc,
                                             float* __restrict__ out) {
  int n = blockIdx.x;
  int c = threadIdx.x;  // 0..63
  int b = n & 31;
  __shared__ float arow[SLEN];
  arow[c] = attn[(size_t)n * SLEN + c];
  arow[c + 64] = attn[(size_t)n * SLEN + 64 + c];
  __syncthreads();
  float s = 0.0f;
  for (int sp = 0; sp < SLEN; sp++)
    s += arow[sp] * src_map[((size_t)sp * 32 + b) * CVOCAB + c];
  out[(size_t)n * OUTW + VOCAB + c] = s * pc[n];
}

extern "C" void kernel_launch(void* const* d_in, const int* in_sizes, int n_in,
                              void* d_out, int out_size, void* d_ws, size_t ws_size,
                              hipStream_t stream) {
  const float* hidden = (const float*)d_in[0];
  const float* attn   = (const float*)d_in[1];
  const float* srcmap = (const float*)d_in[2];
  const float* Wg     = (const float*)d_in[3];
  const float* bg     = (const float*)d_in[4];
  const float* Wc     = (const float*)d_in[5];
  const float* bc     = (const float*)d_in[6];
  float* out = (float*)d_out;

  char* ws = (char*)d_ws;
  float* pc      = (float*)ws;                       // 2048 f32
  float* scale   = (float*)(ws + 8192);              // 2048 f32
  float* partial = (float*)(ws + 16384);             // max(NVT,NVT2)*2048 f32
  size_t partEnd = 16384 + (size_t)NVT * NROWS * 4;  // 3,235,840
  ushort* Abf = (ushort*)(ws + partEnd);             // 2048*1024 bf16
  size_t aEnd = partEnd + (size_t)NROWS * DDIM * 2;
  ushort* Wbf = (ushort*)(ws + aEnd);                // VOCABP2*1024 bf16
  size_t need = aEnd + (size_t)VOCABP2 * DDIM * 2;

  k_pcopy<<<NROWS / 4, 256, 0, stream>>>(hidden, Wc, bc, pc);
  if (ws_size >= need) {
    k_cvtA<<<(NROWS * DDIM / 4) / 256, 256, 0, stream>>>(hidden, Abf);
    k_cvtW<<<VOCABP2, 256, 0, stream>>>(Wg, Wbf);
    k_gemm3<<<8 * NVT2, 512, 0, stream>>>(Abf, Wbf, bg, out, partial);
    k_reduce<<<NROWS / 256, 256, 0, stream>>>(partial, pc, scale, NVT2);
  } else {
    k_gemm<<<dim3(NROWS / 128, NVT), 256, 0, stream>>>(hidden, Wg, bg, out, partial);
    k_reduce<<<NROWS / 256, 256, 0, stream>>>(partial, pc, scale, NVT);
  }
  k_scale<<<NROWS, 256, 0, stream>>>(out, scale);
  k_copy<<<NROWS, 64, 0, stream>>>(attn, srcmap, pc, out);
}